// Round 2
// baseline (47.146 us; speedup 1.0000x reference)
//
#include <hip/hip_runtime.h>

// Depthwise causal conv1d on (B, T, C) fp32.
// y[b,t,c] = sum_{k=0..K-1} w[k,c] * x[b, t+k-(K-1), c], zero-padded left.
// B=4, T=4096, C=2048, K=4.
//
// R1: nontemporal y-stores (keep x L3-resident across graph replays) +
//     TCHUNK 32->64 (halo overhead 9.4% -> 4.7% of reads).

constexpr int K_TAPS = 4;
constexpr int TCHUNK = 64;   // t-rows per block; halo = K-1 = 3 extra row-reads
constexpr int BLOCK  = 256;  // threads; each thread owns 4 channels (float4)

typedef float f32x4 __attribute__((ext_vector_type(4)));

__global__ __launch_bounds__(BLOCK) void shortconv_kernel(
    const float* __restrict__ x,   // (B, T, C)
    const float* __restrict__ w,   // (K, 1, C)
    float* __restrict__ y,         // (B, T, C)
    int B, int T, int C)
{
    const int cblocks = C / (4 * BLOCK);          // float4-groups of channels per row
    const int tblocks = T / TCHUNK;

    int bid = blockIdx.x;
    int cb  = bid % cblocks;
    int tb  = (bid / cblocks) % tblocks;
    int b   =  bid / (cblocks * tblocks);

    int c  = (cb * BLOCK + threadIdx.x) * 4;      // starting channel (float4-aligned)
    int t0 = tb * TCHUNK;

    const float* xb = x + (size_t)b * T * C;
    float*       yb = y + (size_t)b * T * C;

    // Per-channel weights: w[k*C + c .. c+3]
    f32x4 wk[K_TAPS];
#pragma unroll
    for (int k = 0; k < K_TAPS; ++k)
        wk[k] = *reinterpret_cast<const f32x4*>(w + (size_t)k * C + c);

    // Sliding window: win0 = x[t-3], win1 = x[t-2], win2 = x[t-1]
    f32x4 win0 = 0.f, win1 = 0.f, win2 = 0.f;
    if (t0 >= K_TAPS - 1) {   // block-uniform branch
        win0 = *reinterpret_cast<const f32x4*>(xb + (size_t)(t0 - 3) * C + c);
        win1 = *reinterpret_cast<const f32x4*>(xb + (size_t)(t0 - 2) * C + c);
        win2 = *reinterpret_cast<const f32x4*>(xb + (size_t)(t0 - 1) * C + c);
    }

#pragma unroll 4
    for (int i = 0; i < TCHUNK; ++i) {
        int t = t0 + i;
        f32x4 xin = *reinterpret_cast<const f32x4*>(xb + (size_t)t * C + c);
        f32x4 out = wk[0] * win0 + wk[1] * win1 + wk[2] * win2 + wk[3] * xin;
        // Non-temporal store: y is write-once, never re-read by this kernel.
        // Avoid evicting x from L3 with the 134 MB write stream.
        __builtin_nontemporal_store(out, reinterpret_cast<f32x4*>(yb + (size_t)t * C + c));
        win0 = win1; win1 = win2; win2 = xin;
    }
}

extern "C" void kernel_launch(void* const* d_in, const int* in_sizes, int n_in,
                              void* d_out, int out_size, void* d_ws, size_t ws_size,
                              hipStream_t stream) {
    const float* x = (const float*)d_in[0];
    const float* w = (const float*)d_in[1];
    float* y = (float*)d_out;

    const int B = 4, T = 4096, C = 2048;
    const int cblocks = C / (4 * BLOCK);   // 2
    const int tblocks = T / TCHUNK;        // 64
    dim3 grid(B * tblocks * cblocks);      // 512 blocks (2/CU, 8 waves/CU)
    dim3 block(BLOCK);
    shortconv_kernel<<<grid, block, 0, stream>>>(x, w, y, B, T, C);
}

// Round 3
// 46.695 us; speedup vs baseline: 1.0097x; 1.0097x over previous
//
#include <hip/hip_runtime.h>

// Depthwise causal conv1d on (B, T, C) fp32.
// y[b,t,c] = sum_{k=0..K-1} w[k,c] * x[b, t+k-(K-1), c], zero-padded left.
// B=4, T=4096, C=2048, K=4.
//
// R2: batched load/store phases (8 rows per batch) to cluster the read and
//     write streams — reduce DRAM read/write turnaround vs per-row ping-pong.
//     TCHUNK=32, 1024 blocks (R0's best config). nt stores dropped (R1: no-op).

constexpr int K_TAPS = 4;
constexpr int TCHUNK = 32;   // t-rows per block; halo = K-1 = 3 extra row-reads
constexpr int BATCH  = 8;    // rows loaded back-to-back before storing
constexpr int BLOCK  = 256;  // threads; each thread owns 4 channels (float4)

typedef float f32x4 __attribute__((ext_vector_type(4)));

__global__ __launch_bounds__(BLOCK) void shortconv_kernel(
    const float* __restrict__ x,   // (B, T, C)
    const float* __restrict__ w,   // (K, 1, C)
    float* __restrict__ y,         // (B, T, C)
    int B, int T, int C)
{
    const int cblocks = C / (4 * BLOCK);          // float4-groups of channels per row
    const int tblocks = T / TCHUNK;

    int bid = blockIdx.x;
    int cb  = bid % cblocks;
    int tb  = (bid / cblocks) % tblocks;
    int b   =  bid / (cblocks * tblocks);

    int c  = (cb * BLOCK + threadIdx.x) * 4;      // starting channel (float4-aligned)
    int t0 = tb * TCHUNK;

    const float* xb = x + (size_t)b * T * C;
    float*       yb = y + (size_t)b * T * C;

    // Per-channel weights: w[k*C + c .. c+3]
    f32x4 wk[K_TAPS];
#pragma unroll
    for (int k = 0; k < K_TAPS; ++k)
        wk[k] = *reinterpret_cast<const f32x4*>(w + (size_t)k * C + c);

    // Sliding window: win0 = x[t-3], win1 = x[t-2], win2 = x[t-1]
    f32x4 win0 = 0.f, win1 = 0.f, win2 = 0.f;
    if (t0 >= K_TAPS - 1) {   // block-uniform branch
        win0 = *reinterpret_cast<const f32x4*>(xb + (size_t)(t0 - 3) * C + c);
        win1 = *reinterpret_cast<const f32x4*>(xb + (size_t)(t0 - 2) * C + c);
        win2 = *reinterpret_cast<const f32x4*>(xb + (size_t)(t0 - 1) * C + c);
    }

    for (int batch = 0; batch < TCHUNK / BATCH; ++batch) {
        int tbase = t0 + batch * BATCH;

        // Phase 1: 8 independent loads, issued back-to-back (read burst).
        f32x4 xin[BATCH];
#pragma unroll
        for (int j = 0; j < BATCH; ++j)
            xin[j] = *reinterpret_cast<const f32x4*>(xb + (size_t)(tbase + j) * C + c);

        // Phase 2: compute + 8 stores back-to-back (write burst).
#pragma unroll
        for (int j = 0; j < BATCH; ++j) {
            f32x4 out = wk[0] * win0 + wk[1] * win1 + wk[2] * win2 + wk[3] * xin[j];
            *reinterpret_cast<f32x4*>(yb + (size_t)(tbase + j) * C + c) = out;
            win0 = win1; win1 = win2; win2 = xin[j];
        }
    }
}

extern "C" void kernel_launch(void* const* d_in, const int* in_sizes, int n_in,
                              void* d_out, int out_size, void* d_ws, size_t ws_size,
                              hipStream_t stream) {
    const float* x = (const float*)d_in[0];
    const float* w = (const float*)d_in[1];
    float* y = (float*)d_out;

    const int B = 4, T = 4096, C = 2048;
    const int cblocks = C / (4 * BLOCK);   // 2
    const int tblocks = T / TCHUNK;        // 128
    dim3 grid(B * tblocks * cblocks);      // 1024 blocks (4/CU, 16 waves/CU)
    dim3 block(BLOCK);
    shortconv_kernel<<<grid, block, 0, stream>>>(x, w, y, B, T, C);
}